// Round 2
// baseline (534.896 us; speedup 1.0000x reference)
//
#include <hip/hip_runtime.h>
#include <math.h>

#define PI_F 3.14159265358979323846f

// ---------------- zero the scalar output ----------------
__global__ void zero_kernel(float* out) {
    if (threadIdx.x == 0 && blockIdx.x == 0) out[0] = 0.0f;
}

// ---------------- 2x2 area downsample (path A) ----------------
__global__ void down2_kernel(const float* __restrict__ src, float* __restrict__ dst,
                             int C_total, int Hd, int Wd) {
    int idx = blockIdx.x * blockDim.x + threadIdx.x;
    int total = C_total * Hd * Wd;
    if (idx >= total) return;
    int x = idx % Wd;
    int t = idx / Wd;
    int y = t % Hd;
    int c = t / Hd;
    int Ws = Wd * 2;
    const float* sp = src + (((size_t)c * (Hd * 2) + 2 * y) * (size_t)Ws + 2 * x);
    dst[idx] = 0.25f * (sp[0] + sp[1] + sp[Ws] + sp[Ws + 1]);
}

// Rodrigues: pose (tx,ty,tz,rx,ry,rz) -> R row-major, t
__device__ inline void make_Rt(const float* __restrict__ pose, int bn, float R[9], float t[3]) {
    const float* p = pose + bn * 6;
    t[0] = p[0]; t[1] = p[1]; t[2] = p[2];
    float rx = p[3], ry = p[4], rz = p[5];
    float theta = sqrtf(rx * rx + ry * ry + rz * rz);
    float d = fmaxf(theta, 1e-8f);
    float kx = rx / d, ky = ry / d, kz = rz / d;
    float s = sinf(theta), c = cosf(theta), oc = 1.0f - c;
    R[0] = 1.0f - oc * (ky * ky + kz * kz);
    R[1] = -s * kz + oc * kx * ky;
    R[2] =  s * ky + oc * kx * kz;
    R[3] =  s * kz + oc * kx * ky;
    R[4] = 1.0f - oc * (kx * kx + kz * kz);
    R[5] = -s * kx + oc * ky * kz;
    R[6] = -s * ky + oc * kx * kz;
    R[7] =  s * kx + oc * ky * kz;
    R[8] = 1.0f - oc * (kx * kx + ky * ky);
}

// block mean of an s x s tile of a FULL-RES (512x1024) channel plane
template <int SH>
__device__ inline float blockmean(const float* __restrict__ plane, int y, int x) {
    if constexpr (SH == 0) {
        return plane[(y << 10) + x];
    } else {
        constexpr int s = 1 << SH;
        const float* p = plane + ((size_t)(y << SH) << 10) + (x << SH);
        float sum = 0.0f;
#pragma unroll
        for (int dy = 0; dy < s; ++dy) {
#pragma unroll
            for (int dx = 0; dx < s; ++dx) sum += p[(dy << 10) + dx];
        }
        return sum * (1.0f / (float)(s * s));
    }
}

// ---------------- main photometric kernel, one scale ----------------
// FUSED: rr/tg0/tg1 are full-res (512x1024) and downsampling is inline.
// !FUSED: rr/tg0/tg1 are already at level resolution (h x w).
// depth: (B,1,h,w), mask: (B,2,h,w) always at level resolution.
template <int SH, bool FUSED>
__global__ void photo_kernel(const float* __restrict__ rr,
                             const float* __restrict__ depth,
                             const float* __restrict__ mask,
                             const float* __restrict__ tg0,
                             const float* __restrict__ tg1,
                             const float* __restrict__ pose,
                             float* __restrict__ out) {
    constexpr int h = 512 >> SH;
    constexpr int w = 1024 >> SH;
    constexpr int B = 8;
    constexpr int LOG2W = 10 - SH;
    constexpr int LOG2H = 9 - SH;
    constexpr int LP = LOG2W + LOG2H;  // log2(level plane)
    constexpr float inv_count = 1.0f / (float)(B * 3 * h * w);

    int idx = blockIdx.x * blockDim.x + threadIdx.x;
    float acc = 0.0f;
    int total = B * h * w;
    if (idx < total) {
        int x = idx & (w - 1);
        int y = (idx >> LOG2W) & (h - 1);
        int b = idx >> LP;
        int pix = (y << LOG2W) + x;

        // equirect direction
        float lon = (((float)x + 0.5f) / (float)w * 2.0f - 1.0f) * PI_F;
        float lat = -(((float)y + 0.5f) / (float)h * 2.0f - 1.0f) * (0.5f * PI_F);
        float sl = sinf(lon), cl = cosf(lon);
        float slat = sinf(lat), clat = cosf(lat);
        float dxr = clat * sl, dyr = slat, dzr = clat * cl;

        float dep = depth[((size_t)b << LP) + pix];
        float X = dep * dxr, Y = dep * dyr, Z = dep * dzr;

        // ref pixel (3 channels)
        float rc[3];
#pragma unroll
        for (int c = 0; c < 3; ++c) {
            if constexpr (FUSED)
                rc[c] = blockmean<SH>(rr + ((size_t)(b * 3 + c) << 19), y, x);
            else
                rc[c] = rr[((size_t)(b * 3 + c) << LP) + pix];
        }

#pragma unroll
        for (int n = 0; n < 2; ++n) {
            float R[9], t[3];
            make_Rt(pose, b * 2 + n, R, t);
            float px = R[0] * X + R[1] * Y + R[2] * Z + t[0];
            float py = R[3] * X + R[4] * Y + R[5] * Z + t[1];
            float pz = R[6] * X + R[7] * Y + R[8] * Z + t[2];
            float nrm = sqrtf(px * px + py * py + pz * pz);
            float lon2 = atan2f(px, pz);
            float sina = py / fmaxf(nrm, 1e-8f);
            sina = fminf(fmaxf(sina, -1.0f), 1.0f);
            float lat2 = asinf(sina);
            float gx = (lon2 * (1.0f / PI_F) + 1.0f) * 0.5f * (float)(w - 1);
            float gy = (lat2 * (2.0f / PI_F) + 1.0f) * 0.5f * (float)(h - 1);
            float x0f = floorf(gx), y0f = floorf(gy);
            float x1f = x0f + 1.0f, y1f = y0f + 1.0f;
            float wa = (x1f - gx) * (y1f - gy);
            float wb = (x1f - gx) * (gy - y0f);
            float wc = (gx - x0f) * (y1f - gy);
            float wd = (gx - x0f) * (gy - y0f);
            bool vx0 = (x0f >= 0.0f) && (x0f <= (float)(w - 1));
            bool vx1 = (x1f >= 0.0f) && (x1f <= (float)(w - 1));
            bool vy0 = (y0f >= 0.0f) && (y0f <= (float)(h - 1));
            bool vy1 = (y1f >= 0.0f) && (y1f <= (float)(h - 1));
            int xi0 = (int)fminf(fmaxf(x0f, 0.0f), (float)(w - 1));
            int xi1 = (int)fminf(fmaxf(x1f, 0.0f), (float)(w - 1));
            int yi0 = (int)fminf(fmaxf(y0f, 0.0f), (float)(h - 1));
            int yi1 = (int)fminf(fmaxf(y1f, 0.0f), (float)(h - 1));
            float waf = (vx0 && vy0) ? wa : 0.0f;
            float wbf = (vx0 && vy1) ? wb : 0.0f;
            float wcf = (vx1 && vy0) ? wc : 0.0f;
            float wdf = (vx1 && vy1) ? wd : 0.0f;

            const float* tg = (n == 0) ? tg0 : tg1;
            float m = mask[((size_t)(b * 2 + n) << LP) + pix];

#pragma unroll
            for (int c = 0; c < 3; ++c) {
                float va, vb2, vc2, vd2;
                if constexpr (FUSED) {
                    const float* plane = tg + ((size_t)(b * 3 + c) << 19);
                    va  = blockmean<SH>(plane, yi0, xi0);
                    vb2 = blockmean<SH>(plane, yi1, xi0);
                    vc2 = blockmean<SH>(plane, yi0, xi1);
                    vd2 = blockmean<SH>(plane, yi1, xi1);
                } else {
                    const float* plane = tg + ((size_t)(b * 3 + c) << LP);
                    va  = plane[(yi0 << LOG2W) + xi0];
                    vb2 = plane[(yi1 << LOG2W) + xi0];
                    vc2 = plane[(yi0 << LOG2W) + xi1];
                    vd2 = plane[(yi1 << LOG2W) + xi1];
                }
                float v = waf * va + wbf * vb2 + wcf * vc2 + wdf * vd2;
                acc += m * fabsf(rc[c] - v);
            }
        }
        acc *= inv_count;
    }

    // block reduction: wave64 shuffle then LDS across waves
    for (int off = 32; off > 0; off >>= 1) acc += __shfl_down(acc, off);
    __shared__ float wsum[4];
    int lane = threadIdx.x & 63;
    int wid = threadIdx.x >> 6;
    if (lane == 0) wsum[wid] = acc;
    __syncthreads();
    if (threadIdx.x == 0) {
        atomicAdd(out, wsum[0] + wsum[1] + wsum[2] + wsum[3]);
    }
}

extern "C" void kernel_launch(void* const* d_in, const int* in_sizes, int n_in,
                              void* d_out, int out_size, void* d_ws, size_t ws_size,
                              hipStream_t stream) {
    // setup_inputs dict order: ref_rgb, (ref_depth{i}, exp_mask{i}) for i=0..3,
    // tgt_rgb0, tgt_rgb1, pose   <-- depth/mask INTERLEAVED
    const float* ref  = (const float*)d_in[0];
    const float* dep0 = (const float*)d_in[1];
    const float* msk0 = (const float*)d_in[2];
    const float* dep1 = (const float*)d_in[3];
    const float* msk1 = (const float*)d_in[4];
    const float* dep2 = (const float*)d_in[5];
    const float* msk2 = (const float*)d_in[6];
    const float* dep3 = (const float*)d_in[7];
    const float* msk3 = (const float*)d_in[8];
    const float* tgt0 = (const float*)d_in[9];
    const float* tgt1 = (const float*)d_in[10];
    const float* pose = (const float*)d_in[11];
    float* out = (float*)d_out;

    zero_kernel<<<1, 64, 0, stream>>>(out);

    const size_t L1 = (size_t)24 * 256 * 512;
    const size_t L2 = (size_t)24 * 128 * 256;
    const size_t L3 = (size_t)24 * 64 * 128;
    const size_t NEED_BYTES = 3 * (L1 + L2 + L3) * sizeof(float);

    if (ws_size >= NEED_BYTES) {
        // ---- path A: precompute pyramid in workspace ----
        float* p = (float*)d_ws;
        float* ref_l1 = p; p += L1;
        float* ref_l2 = p; p += L2;
        float* ref_l3 = p; p += L3;
        float* t0_l1 = p; p += L1;
        float* t0_l2 = p; p += L2;
        float* t0_l3 = p; p += L3;
        float* t1_l1 = p; p += L1;
        float* t1_l2 = p; p += L2;
        float* t1_l3 = p; p += L3;

        auto down = [&](const float* src, float* dst, int Hd, int Wd) {
            int total = 24 * Hd * Wd;
            down2_kernel<<<(total + 255) / 256, 256, 0, stream>>>(src, dst, 24, Hd, Wd);
        };
        down(ref, ref_l1, 256, 512);
        down(ref_l1, ref_l2, 128, 256);
        down(ref_l2, ref_l3, 64, 128);
        down(tgt0, t0_l1, 256, 512);
        down(t0_l1, t0_l2, 128, 256);
        down(t0_l2, t0_l3, 64, 128);
        down(tgt1, t1_l1, 256, 512);
        down(t1_l1, t1_l2, 128, 256);
        down(t1_l2, t1_l3, 64, 128);

        photo_kernel<0, false><<<(8 * 512 * 1024 + 255) / 256, 256, 0, stream>>>(
            ref, dep0, msk0, tgt0, tgt1, pose, out);
        photo_kernel<1, false><<<(8 * 256 * 512 + 255) / 256, 256, 0, stream>>>(
            ref_l1, dep1, msk1, t0_l1, t1_l1, pose, out);
        photo_kernel<2, false><<<(8 * 128 * 256 + 255) / 256, 256, 0, stream>>>(
            ref_l2, dep2, msk2, t0_l2, t1_l2, pose, out);
        photo_kernel<3, false><<<(8 * 64 * 128 + 255) / 256, 256, 0, stream>>>(
            ref_l3, dep3, msk3, t0_l3, t1_l3, pose, out);
    } else {
        // ---- path B: zero-workspace, downsample fused into the photo kernel ----
        photo_kernel<0, false><<<(8 * 512 * 1024 + 255) / 256, 256, 0, stream>>>(
            ref, dep0, msk0, tgt0, tgt1, pose, out);
        photo_kernel<1, true><<<(8 * 256 * 512 + 255) / 256, 256, 0, stream>>>(
            ref, dep1, msk1, tgt0, tgt1, pose, out);
        photo_kernel<2, true><<<(8 * 128 * 256 + 255) / 256, 256, 0, stream>>>(
            ref, dep2, msk2, tgt0, tgt1, pose, out);
        photo_kernel<3, true><<<(8 * 64 * 128 + 255) / 256, 256, 0, stream>>>(
            ref, dep3, msk3, tgt0, tgt1, pose, out);
    }
}

// Round 3
// 499.471 us; speedup vs baseline: 1.0709x; 1.0709x over previous
//
#include <hip/hip_runtime.h>
#include <math.h>

#define PI_F 3.14159265358979323846f

// ---------------- fast atan2 (minimax deg-11, max err ~1e-5 rad) ----------------
__device__ inline float fast_atan2f(float y, float x) {
    float ax = fabsf(x), ay = fabsf(y);
    float mx = fmaxf(ax, ay);
    float mn = fminf(ax, ay);
    float a = __fdividef(mn, fmaxf(mx, 1e-30f));
    float s = a * a;
    float r = fmaf(s, fmaf(s, fmaf(s, fmaf(s, fmaf(s, -0.01172120f, 0.05265332f),
                   -0.11643287f), 0.19354346f), -0.33262347f), 0.99997726f);
    r = r * a;
    if (ay > ax) r = 1.57079632679f - r;
    if (x < 0.0f) r = PI_F - r;
    return copysignf(r, y);
}

// Rodrigues: pose (tx,ty,tz,rx,ry,rz) -> o[0..8]=R row-major, o[9..11]=t
__device__ inline void make_Rt_to(const float* __restrict__ pose, int bn, float* __restrict__ o) {
    const float* p = pose + bn * 6;
    float tx = p[0], ty = p[1], tz = p[2];
    float rx = p[3], ry = p[4], rz = p[5];
    float theta = sqrtf(rx * rx + ry * ry + rz * rz);
    float inv = __fdividef(1.0f, fmaxf(theta, 1e-8f));
    float kx = rx * inv, ky = ry * inv, kz = rz * inv;
    float s, c;
    __sincosf(theta, &s, &c);
    float oc = 1.0f - c;
    o[0] = 1.0f - oc * (ky * ky + kz * kz);
    o[1] = -s * kz + oc * kx * ky;
    o[2] =  s * ky + oc * kx * kz;
    o[3] =  s * kz + oc * kx * ky;
    o[4] = 1.0f - oc * (kx * kx + kz * kz);
    o[5] = -s * kx + oc * ky * kz;
    o[6] = -s * ky + oc * kx * kz;
    o[7] =  s * kx + oc * ky * kz;
    o[8] = 1.0f - oc * (kx * kx + ky * ky);
    o[9] = tx; o[10] = ty; o[11] = tz;
}

// ---------------- fused 2x downsample of ref/tgt0/tgt1, one level ----------------
// LWD = log2(dst width). dst: (24, 1<<(LWD-1), 1<<LWD), src: 2x each dim.
// blockIdx.y in [0,3) selects image. Each thread: 2 dst px via float4 reads.
template <int LWD>
__global__ __launch_bounds__(256) void down3_kernel(const float* __restrict__ sA,
                                                    const float* __restrict__ sB,
                                                    const float* __restrict__ sC,
                                                    float* __restrict__ dA,
                                                    float* __restrict__ dB,
                                                    float* __restrict__ dC) {
    const float* src = (blockIdx.y == 0) ? sA : (blockIdx.y == 1) ? sB : sC;
    float* dst = (blockIdx.y == 0) ? dA : (blockIdx.y == 1) ? dB : dC;
    int idx = blockIdx.x * 256 + threadIdx.x;
    constexpr int HB = LWD - 1;                 // bits for xpair and y
    int xp = idx & ((1 << HB) - 1);
    int y = (idx >> HB) & ((1 << HB) - 1);
    int c = idx >> (2 * HB);                    // [0,24)
    const float* sp = src + ((size_t)c << (2 * LWD + 1)) + ((size_t)(2 * y) << (LWD + 1)) + 4 * xp;
    float4 r0 = *(const float4*)sp;
    float4 r1 = *(const float4*)(sp + (1 << (LWD + 1)));
    float2 d;
    d.x = 0.25f * (r0.x + r0.y + r1.x + r1.y);
    d.y = 0.25f * (r0.z + r0.w + r1.z + r1.w);
    *(float2*)(dst + ((size_t)c << (2 * LWD - 1)) + ((size_t)y << LWD) + 2 * xp) = d;
}

// ---------------- per-scale photometric body (level-resolution inputs) ----------------
template <int SH>
__device__ inline float photo_scale(int bidl, int tid,
                                    const float* __restrict__ rr,
                                    const float* __restrict__ depth,
                                    const float* __restrict__ mask,
                                    const float* __restrict__ tg0,
                                    const float* __restrict__ tg1,
                                    const float* __restrict__ pose,
                                    float* __restrict__ ldsRt) {
    constexpr int h = 512 >> SH;
    constexpr int w = 1024 >> SH;
    constexpr int LOG2W = 10 - SH;
    constexpr int LP = 19 - 2 * SH;
    constexpr float inv_count = 1.0f / (8.0f * 3.0f * h * w);

    int lidx = (bidl << 8) + tid;
    int b = lidx >> LP;  // block-uniform
    if (tid < 2) make_Rt_to(pose, b * 2 + tid, ldsRt + tid * 12);
    __syncthreads();

    int x = lidx & (w - 1);
    int y = (lidx >> LOG2W) & (h - 1);
    int pix = (y << LOG2W) + x;

    float lon = (((float)x + 0.5f) * (2.0f / (float)w) - 1.0f) * PI_F;
    float lat = -(((float)y + 0.5f) * (2.0f / (float)h) - 1.0f) * (0.5f * PI_F);
    float sl = __sinf(lon), cl = __cosf(lon);
    float slat = __sinf(lat), clat = __cosf(lat);

    float dep = depth[((size_t)b << LP) + pix];
    float X = dep * clat * sl, Y = dep * slat, Z = dep * clat * cl;

    float rc[3];
#pragma unroll
    for (int c = 0; c < 3; ++c)
        rc[c] = rr[((size_t)(b * 3 + c) << LP) + pix];

    float acc = 0.0f;
#pragma unroll
    for (int n = 0; n < 2; ++n) {
        const float* R = ldsRt + n * 12;
        float px = R[0] * X + R[1] * Y + R[2] * Z + R[9];
        float py = R[3] * X + R[4] * Y + R[5] * Z + R[10];
        float pz = R[6] * X + R[7] * Y + R[8] * Z + R[11];
        float rxz = sqrtf(px * px + pz * pz);
        float lon2 = fast_atan2f(px, pz);
        float lat2 = fast_atan2f(py, rxz);   // == asin(clip(py/norm))
        float gx = (lon2 * (1.0f / PI_F) + 1.0f) * 0.5f * (float)(w - 1);
        float gy = (lat2 * (2.0f / PI_F) + 1.0f) * 0.5f * (float)(h - 1);
        float x0f = floorf(gx), y0f = floorf(gy);
        float fx = gx - x0f, fy = gy - y0f;
        float wa = (1.0f - fx) * (1.0f - fy);
        float wb = (1.0f - fx) * fy;
        float wc = fx * (1.0f - fy);
        float wd = fx * fy;
        bool vx0 = (x0f >= 0.0f) && (x0f <= (float)(w - 1));
        bool vx1 = (x0f >= -1.0f) && (x0f <= (float)(w - 2));
        bool vy0 = (y0f >= 0.0f) && (y0f <= (float)(h - 1));
        bool vy1 = (y0f >= -1.0f) && (y0f <= (float)(h - 2));
        int xi0 = (int)fminf(fmaxf(x0f, 0.0f), (float)(w - 1));
        int xi1 = (int)fminf(fmaxf(x0f + 1.0f, 0.0f), (float)(w - 1));
        int yi0 = (int)fminf(fmaxf(y0f, 0.0f), (float)(h - 1));
        int yi1 = (int)fminf(fmaxf(y0f + 1.0f, 0.0f), (float)(h - 1));
        float waf = (vx0 && vy0) ? wa : 0.0f;
        float wbf = (vx0 && vy1) ? wb : 0.0f;
        float wcf = (vx1 && vy0) ? wc : 0.0f;
        float wdf = (vx1 && vy1) ? wd : 0.0f;
        int ia = (yi0 << LOG2W) + xi0;
        int ib = (yi1 << LOG2W) + xi0;
        int ic = (yi0 << LOG2W) + xi1;
        int id = (yi1 << LOG2W) + xi1;

        const float* tg = (n == 0) ? tg0 : tg1;
        float m = mask[((size_t)(b * 2 + n) << LP) + pix];

#pragma unroll
        for (int c = 0; c < 3; ++c) {
            const float* plane = tg + ((size_t)(b * 3 + c) << LP);
            float v = waf * plane[ia] + wbf * plane[ib] + wcf * plane[ic] + wdf * plane[id];
            acc += m * fabsf(rc[c] - v);
        }
    }
    return acc * inv_count;
}

// ---------------- single multi-scale photometric kernel (path A) ----------------
__global__ __launch_bounds__(256) void photo_all_kernel(
    const float* __restrict__ rr0, const float* __restrict__ dep0, const float* __restrict__ msk0,
    const float* __restrict__ tA0, const float* __restrict__ tB0,
    const float* __restrict__ rr1, const float* __restrict__ dep1, const float* __restrict__ msk1,
    const float* __restrict__ tA1, const float* __restrict__ tB1,
    const float* __restrict__ rr2, const float* __restrict__ dep2, const float* __restrict__ msk2,
    const float* __restrict__ tA2, const float* __restrict__ tB2,
    const float* __restrict__ rr3, const float* __restrict__ dep3, const float* __restrict__ msk3,
    const float* __restrict__ tA3, const float* __restrict__ tB3,
    const float* __restrict__ pose, float* __restrict__ out) {
    __shared__ float ldsRt[24];
    __shared__ float wsum[4];
    int bid = blockIdx.x, tid = threadIdx.x;
    float acc;
    if (bid < 16384)
        acc = photo_scale<0>(bid, tid, rr0, dep0, msk0, tA0, tB0, pose, ldsRt);
    else if (bid < 20480)
        acc = photo_scale<1>(bid - 16384, tid, rr1, dep1, msk1, tA1, tB1, pose, ldsRt);
    else if (bid < 21504)
        acc = photo_scale<2>(bid - 20480, tid, rr2, dep2, msk2, tA2, tB2, pose, ldsRt);
    else
        acc = photo_scale<3>(bid - 21504, tid, rr3, dep3, msk3, tA3, tB3, pose, ldsRt);

    for (int off = 32; off > 0; off >>= 1) acc += __shfl_down(acc, off);
    if ((tid & 63) == 0) wsum[tid >> 6] = acc;
    __syncthreads();
    if (tid == 0) atomicAdd(out, wsum[0] + wsum[1] + wsum[2] + wsum[3]);
}

// ---------------- fallback: per-scale kernel with fused inline downsample ----------------
template <int SH>
__device__ inline float blockmean_full(const float* __restrict__ plane, int y, int x) {
    if constexpr (SH == 0) {
        return plane[(y << 10) + x];
    } else {
        constexpr int s = 1 << SH;
        const float* p = plane + ((size_t)(y << SH) << 10) + (x << SH);
        float sum = 0.0f;
#pragma unroll
        for (int dy = 0; dy < s; ++dy)
#pragma unroll
            for (int dx = 0; dx < s; ++dx) sum += p[(dy << 10) + dx];
        return sum * (1.0f / (float)(s * s));
    }
}

template <int SH>
__global__ __launch_bounds__(256) void photo_fused_kernel(
    const float* __restrict__ rr, const float* __restrict__ depth, const float* __restrict__ mask,
    const float* __restrict__ tg0, const float* __restrict__ tg1,
    const float* __restrict__ pose, float* __restrict__ out) {
    constexpr int h = 512 >> SH;
    constexpr int w = 1024 >> SH;
    constexpr int LOG2W = 10 - SH;
    constexpr int LP = 19 - 2 * SH;
    constexpr float inv_count = 1.0f / (8.0f * 3.0f * h * w);
    __shared__ float ldsRt[24];
    __shared__ float wsum[4];
    int tid = threadIdx.x;
    int lidx = blockIdx.x * 256 + tid;
    int b = lidx >> LP;
    if (tid < 2) make_Rt_to(pose, b * 2 + tid, ldsRt + tid * 12);
    __syncthreads();

    int x = lidx & (w - 1);
    int y = (lidx >> LOG2W) & (h - 1);
    int pix = (y << LOG2W) + x;
    float lon = (((float)x + 0.5f) * (2.0f / (float)w) - 1.0f) * PI_F;
    float lat = -(((float)y + 0.5f) * (2.0f / (float)h) - 1.0f) * (0.5f * PI_F);
    float sl = __sinf(lon), cl = __cosf(lon);
    float slat = __sinf(lat), clat = __cosf(lat);
    float dep = depth[((size_t)b << LP) + pix];
    float X = dep * clat * sl, Y = dep * slat, Z = dep * clat * cl;

    float rc[3];
#pragma unroll
    for (int c = 0; c < 3; ++c)
        rc[c] = blockmean_full<SH>(rr + ((size_t)(b * 3 + c) << 19), y, x);

    float acc = 0.0f;
#pragma unroll
    for (int n = 0; n < 2; ++n) {
        const float* R = ldsRt + n * 12;
        float px = R[0] * X + R[1] * Y + R[2] * Z + R[9];
        float py = R[3] * X + R[4] * Y + R[5] * Z + R[10];
        float pz = R[6] * X + R[7] * Y + R[8] * Z + R[11];
        float rxz = sqrtf(px * px + pz * pz);
        float lon2 = fast_atan2f(px, pz);
        float lat2 = fast_atan2f(py, rxz);
        float gx = (lon2 * (1.0f / PI_F) + 1.0f) * 0.5f * (float)(w - 1);
        float gy = (lat2 * (2.0f / PI_F) + 1.0f) * 0.5f * (float)(h - 1);
        float x0f = floorf(gx), y0f = floorf(gy);
        float fx = gx - x0f, fy = gy - y0f;
        float wa = (1.0f - fx) * (1.0f - fy);
        float wb = (1.0f - fx) * fy;
        float wc = fx * (1.0f - fy);
        float wd = fx * fy;
        bool vx0 = (x0f >= 0.0f) && (x0f <= (float)(w - 1));
        bool vx1 = (x0f >= -1.0f) && (x0f <= (float)(w - 2));
        bool vy0 = (y0f >= 0.0f) && (y0f <= (float)(h - 1));
        bool vy1 = (y0f >= -1.0f) && (y0f <= (float)(h - 2));
        int xi0 = (int)fminf(fmaxf(x0f, 0.0f), (float)(w - 1));
        int xi1 = (int)fminf(fmaxf(x0f + 1.0f, 0.0f), (float)(w - 1));
        int yi0 = (int)fminf(fmaxf(y0f, 0.0f), (float)(h - 1));
        int yi1 = (int)fminf(fmaxf(y0f + 1.0f, 0.0f), (float)(h - 1));
        float waf = (vx0 && vy0) ? wa : 0.0f;
        float wbf = (vx0 && vy1) ? wb : 0.0f;
        float wcf = (vx1 && vy0) ? wc : 0.0f;
        float wdf = (vx1 && vy1) ? wd : 0.0f;
        const float* tg = (n == 0) ? tg0 : tg1;
        float m = mask[((size_t)(b * 2 + n) << LP) + pix];
#pragma unroll
        for (int c = 0; c < 3; ++c) {
            const float* plane = tg + ((size_t)(b * 3 + c) << 19);
            float va  = blockmean_full<SH>(plane, yi0, xi0);
            float vb2 = blockmean_full<SH>(plane, yi1, xi0);
            float vc2 = blockmean_full<SH>(plane, yi0, xi1);
            float vd2 = blockmean_full<SH>(plane, yi1, xi1);
            acc += m * fabsf(rc[c] - (waf * va + wbf * vb2 + wcf * vc2 + wdf * vd2));
        }
    }
    acc *= inv_count;

    for (int off = 32; off > 0; off >>= 1) acc += __shfl_down(acc, off);
    if ((tid & 63) == 0) wsum[tid >> 6] = acc;
    __syncthreads();
    if (tid == 0) atomicAdd(out, wsum[0] + wsum[1] + wsum[2] + wsum[3]);
}

extern "C" void kernel_launch(void* const* d_in, const int* in_sizes, int n_in,
                              void* d_out, int out_size, void* d_ws, size_t ws_size,
                              hipStream_t stream) {
    // dict order: ref_rgb, (ref_depth{i}, exp_mask{i}) i=0..3, tgt_rgb0, tgt_rgb1, pose
    const float* ref  = (const float*)d_in[0];
    const float* dep0 = (const float*)d_in[1];
    const float* msk0 = (const float*)d_in[2];
    const float* dep1 = (const float*)d_in[3];
    const float* msk1 = (const float*)d_in[4];
    const float* dep2 = (const float*)d_in[5];
    const float* msk2 = (const float*)d_in[6];
    const float* dep3 = (const float*)d_in[7];
    const float* msk3 = (const float*)d_in[8];
    const float* tgt0 = (const float*)d_in[9];
    const float* tgt1 = (const float*)d_in[10];
    const float* pose = (const float*)d_in[11];
    float* out = (float*)d_out;

    hipMemsetAsync(out, 0, sizeof(float), stream);

    const size_t L1 = (size_t)24 * 256 * 512;
    const size_t L2 = (size_t)24 * 128 * 256;
    const size_t L3 = (size_t)24 * 64 * 128;
    const size_t NEED_BYTES = 3 * (L1 + L2 + L3) * sizeof(float);

    if (ws_size >= NEED_BYTES) {
        float* p = (float*)d_ws;
        float* ref_l1 = p; p += L1;
        float* ref_l2 = p; p += L2;
        float* ref_l3 = p; p += L3;
        float* t0_l1 = p; p += L1;
        float* t0_l2 = p; p += L2;
        float* t0_l3 = p; p += L3;
        float* t1_l1 = p; p += L1;
        float* t1_l2 = p; p += L2;
        float* t1_l3 = p; p += L3;

        // L1: 24*256*256 threads per image
        down3_kernel<9><<<dim3((24 << 16) / 256, 3), 256, 0, stream>>>(
            ref, tgt0, tgt1, ref_l1, t0_l1, t1_l1);
        down3_kernel<8><<<dim3((24 << 14) / 256, 3), 256, 0, stream>>>(
            ref_l1, t0_l1, t1_l1, ref_l2, t0_l2, t1_l2);
        down3_kernel<7><<<dim3((24 << 12) / 256, 3), 256, 0, stream>>>(
            ref_l2, t0_l2, t1_l2, ref_l3, t0_l3, t1_l3);

        photo_all_kernel<<<21760, 256, 0, stream>>>(
            ref, dep0, msk0, tgt0, tgt1,
            ref_l1, dep1, msk1, t0_l1, t1_l1,
            ref_l2, dep2, msk2, t0_l2, t1_l2,
            ref_l3, dep3, msk3, t0_l3, t1_l3,
            pose, out);
    } else {
        photo_fused_kernel<0><<<16384, 256, 0, stream>>>(ref, dep0, msk0, tgt0, tgt1, pose, out);
        photo_fused_kernel<1><<<4096, 256, 0, stream>>>(ref, dep1, msk1, tgt0, tgt1, pose, out);
        photo_fused_kernel<2><<<1024, 256, 0, stream>>>(ref, dep2, msk2, tgt0, tgt1, pose, out);
        photo_fused_kernel<3><<<256, 256, 0, stream>>>(ref, dep3, msk3, tgt0, tgt1, pose, out);
    }
}